// Round 25
// baseline (884.673 us; speedup 1.0000x reference)
//
#include <hip/hip_runtime.h>
#include <cstdint>
#include <cstddef>

// ---------------------------------------------------------------------------
// TransformerEncoderLayer on MI355X (gfx950).
// Split format: x ~ (hi + lo)/s, lo unscaled residual; 3 MFMAs into ONE acc.
// QKV/out_proj: 128x256 split dbuf core (grids 768/256, verified round 21).
// MoE: 256x256 f16 dbuf core. Gate fused in LN1.
// Attention: fused flash QB=128, dbuf K/V + T14 + T13.
// ROUND 25: attn drops P-lo and V-lo (o2 accumulator gone: PV 24->8 MFMA/iter,
// shfl 32->16; error bound ~1e-3 vs 0.10875 threshold). 3 LDS planes, FLD 68
// -> 52KB dbuf -> 3 blocks/CU. K/Q keep full split (exp-amplified).
// Launches: 10 (round-24 fusion + aliasing discipline).
// Gate RNG: partitionable threefry, b1^b2 (VERIFIED round 5 — DO NOT TOUCH).
// ---------------------------------------------------------------------------

typedef _Float16 h16;
typedef h16 h16x8 __attribute__((ext_vector_type(8)));
typedef h16 h16x4 __attribute__((ext_vector_type(4)));
typedef __fp16 fp16x2 __attribute__((ext_vector_type(2)));
typedef float f32x4 __attribute__((ext_vector_type(4)));
typedef uint32_t u32;

#define DM 1024
#define NH 16
#define HD 64
#define SEQ 1024
#define BB 8
#define BS (BB*SEQ)
#define NBH (BB*NH)
#define NE 4
#define DFE 1024
#define QB 128           /* q-rows per attention block (8 waves x 16) */
#define NCHUNK 16        /* KV tiles of 64 */
#define SLDA 32
#define FLD 68           /* 3-plane attn LDS stride (uniform 8-access banks) */
#define NPOS 9216

#define MFMA16(a,b,c) __builtin_amdgcn_mfma_f32_16x16x32_f16(a,b,c,0,0,0)

// ---- workspace layout (bytes). E = one h16 plane of [8192][1024]. ----
// ALIASING DISCIPLINE: 8E..9E = KL during attention, W1H/W2H after (k_prepw
// MUST launch after k_attn). 5E..8E = Q/K-hi during attn, X/XH after.
static constexpr size_t E = (size_t)BS*DM*2;
static constexpr size_t OFF_QKH = 0;
static constexpr size_t OFF_QKL = E;
static constexpr size_t OFF_SRCH= 2*E;
static constexpr size_t OFF_SRCL= 3*E;
static constexpr size_t OFF_W3H = 4*E;
static constexpr size_t OFF_W3L = 4*E + (size_t)3*DM*DM*2;
static constexpr size_t OFF_WOH = 4*E + (size_t)6*DM*DM*2;
static constexpr size_t OFF_WOL = 4*E + (size_t)7*DM*DM*2;
static constexpr size_t OFF_QH  = 5*E;
static constexpr size_t OFF_QL  = 6*E;
static constexpr size_t OFF_KH  = 7*E;
static constexpr size_t OFF_KL  = 8*E;
static constexpr size_t OFF_VH  = 9*E;
static constexpr size_t OFF_VL  = 10*E;   /* dead (attn no longer reads V-lo) */
static constexpr size_t OFF_OH  = 0;
static constexpr size_t OFF_OL  = E;
static constexpr size_t OFF_ATT = 2*E;
static constexpr size_t OFF_X   = 5*E;
static constexpr size_t OFF_XH  = 7*E;
static constexpr size_t OFF_W1H = 8*E;
static constexpr size_t OFF_W2H = 8*E + (size_t)NE*DFE*DM*2;
static constexpr size_t OFF_HH  = 9*E;
static constexpr size_t OFF_Y   = 11*E;
static constexpr size_t OFF_CHOSEN = 13*E;
static constexpr size_t OFF_COUNTS = 13*E + 32768;
static constexpr size_t OFF_CURSOR = OFF_COUNTS + 16;
static constexpr size_t OFF_EOFF   = OFF_CURSOR + 16;
static constexpr size_t OFF_PLIST  = OFF_EOFF + 16;
static constexpr size_t WS_NEEDED  = OFF_PLIST + (size_t)NPOS*4;

// prep kernel block ranges (all exact, 256 thr, 4 floats/thread)
#define NB_IN  8192   /* BS*DM/4/256      */
#define NB_W3  3072   /* 3*DM*DM/4/256    */
#define NB_WO  1024   /* DM*DM/4/256      */
#define NB_PREP (NB_IN+NB_W3+NB_WO)          /* 12288 */
#define NB_W1  4096   /* NE*DFE*DM/4/256  */
#define NB_PREPW (2*NB_W1)                   /* 8192  */

// ---------------------------------------------------------------------------
__device__ __forceinline__ void store_split(h16* H, h16* L, size_t idx, float v) {
  h16 h = (h16)v;
  H[idx] = h;
  L[idx] = (h16)(v - (float)h);
}

__device__ __forceinline__ float wave_sum(float v) {
  #pragma unroll
  for (int o = 32; o; o >>= 1) v += __shfl_xor(v, o);
  return v;
}

__device__ __forceinline__ u32 pk2w(float a, float b) {
  union { fp16x2 h; u32 w; } u;
  u.h = __builtin_amdgcn_cvt_pkrtz(a, b);
  return u.w;
}

__device__ __forceinline__ void gload16(const void* g, void* l) {
  __builtin_amdgcn_global_load_lds(
      (const __attribute__((address_space(1))) u32*)g,
      (__attribute__((address_space(3))) u32*)l, 16, 0, 0);
}

// ---------------------------------------------------------------------------
// 128(M)x256(N) split-f16 MERGED-ACC core, DOUBLE-BUFFERED (verified r21).
// ---------------------------------------------------------------------------
__device__ __forceinline__ void gemm128x256_core(
    const h16* __restrict__ Ah, const h16* __restrict__ Al,
    const h16* __restrict__ Bh, const h16* __restrict__ Bl,
    int K, int lda, int ldb, int m0, int n0,
    f32x4 (&acc)[4][4], h16* lds)
{
  constexpr int ROWS = 768;
  constexpr int BUF = ROWS*SLDA;
  const int tid = threadIdx.x, lane = tid & 63, wid = tid >> 6;
  const int wr = (wid >> 2) * 64, wc = (wid & 3) * 64;
  const int lr16 = lane >> 2, lgrp = lane & 3;
  const int sw = (lr16 >> 1) & 3;
  const int colo = (lgrp ^ sw) << 3;
  const h16* gptr[6];
  long gaddr[6];
  int ldsoff[6];
  #pragma unroll
  for (int g = 0; g < 6; ++g) {
    const int R0 = wid*96 + g*16;
    const h16* gp; int prow, ld, base0;
    if (R0 < 128)      { gp = Ah; prow = R0;       ld = lda; base0 = m0; }
    else if (R0 < 256) { gp = Al; prow = R0 - 128; ld = lda; base0 = m0; }
    else if (R0 < 512) { gp = Bh; prow = R0 - 256; ld = ldb; base0 = n0; }
    else               { gp = Bl; prow = R0 - 512; ld = ldb; base0 = n0; }
    gptr[g]   = gp;
    gaddr[g]  = (long)(base0 + prow + lr16) * ld + colo;
    ldsoff[g] = R0 * SLDA;
  }
  const int fr = lane & 15, gi = lane >> 4;
  const int pcol = ((gi ^ ((lane >> 1) & 3)) << 3);
  const int nt = K >> 5;

  auto stage = [&](int t, int buf) {
    const long k0 = (long)t << 5;
    h16* lbase = lds + buf*BUF;
    #pragma unroll
    for (int g = 0; g < 6; ++g)
      gload16(gptr[g] + gaddr[g] + k0, lbase + ldsoff[g]);
  };

  stage(0, 0);
  __syncthreads();
  int cur = 0;
  for (int t = 0; t < nt; ++t) {
    if (t + 1 < nt) stage(t + 1, cur ^ 1);
    h16* base = lds + cur*BUF;
    h16* sAh_ = base;
    h16* sAl_ = base + 128*SLDA;
    h16* sBh_ = base + 256*SLDA;
    h16* sBl_ = base + 512*SLDA;
    h16x8 bh[4], bl[4];
    #pragma unroll
    for (int j = 0; j < 4; ++j) {
      bh[j] = *(const h16x8*)(sBh_ + (wc + j*16 + fr)*SLDA + pcol);
      bl[j] = *(const h16x8*)(sBl_ + (wc + j*16 + fr)*SLDA + pcol);
    }
    __builtin_amdgcn_s_setprio(1);
    #pragma unroll
    for (int i = 0; i < 4; ++i) {
      h16x8 ah = *(const h16x8*)(sAh_ + (wr + i*16 + fr)*SLDA + pcol);
      h16x8 al = *(const h16x8*)(sAl_ + (wr + i*16 + fr)*SLDA + pcol);
      #pragma unroll
      for (int j = 0; j < 4; ++j) {
        acc[i][j] = MFMA16(ah, bh[j], acc[i][j]);
        acc[i][j] = MFMA16(ah, bl[j], acc[i][j]);
        acc[i][j] = MFMA16(al, bh[j], acc[i][j]);
      }
    }
    __builtin_amdgcn_s_setprio(0);
    __syncthreads();
    cur ^= 1;
  }
}

#define EPI_128x256 \
  const int lane = threadIdx.x & 63, wid = threadIdx.x >> 6; \
  const int wr = (wid>>2)*64, wc = (wid&3)*64; \
  const int fr = lane & 15, rb = (lane>>4)*4;

#define EPI_256 \
  const int lane = threadIdx.x & 63, wid = threadIdx.x >> 6; \
  const int wr = (wid>>2)*128, wc = (wid&3)*64; \
  const int fr = lane & 15, rb = (lane>>4)*4;

// ---------------------------------------------------------------------------
// 256x256 f16 SINGLE-PLANE core for MoE, DOUBLE-BUFFERED (verified round 18).
// ---------------------------------------------------------------------------
template<bool GATHER>
__device__ __forceinline__ void hgemm256_core(
    const h16* __restrict__ A, const h16* __restrict__ B,
    int K, int lda, int ldb, int m0, int n0, const int* __restrict__ rowmap,
    f32x4 (&acc)[8][4], h16* lds)
{
  constexpr int BUF = 2*256*SLDA;
  const int tid = threadIdx.x, lane = tid & 63, wid = tid >> 6;
  const int wr = (wid >> 2) * 128, wc = (wid & 3) * 64;
  const int lr16 = lane >> 2, lgrp = lane & 3;
  const int plane = wid >> 2;
  const int qrow  = (wid & 3) * 64;
  const int sw = (lr16 >> 1) & 3;
  const int colo = (lgrp ^ sw) << 3;
  const h16* gp = plane ? B : A;
  const int ld  = plane ? ldb : lda;
  long g0[4];
  #pragma unroll
  for (int g = 0; g < 4; ++g) {
    int lrow = qrow + g*16 + lr16;
    long grow;
    if (GATHER && plane == 0) {
      int t = rowmap[m0 + lrow]; if (t < 0) t = 0;
      grow = t;
    } else {
      grow = (plane ? n0 : m0) + lrow;
    }
    g0[g] = grow * (long)ld + colo;
  }
  const int lo = plane*(256*SLDA) + qrow*SLDA;
  const int fr = lane & 15, gi = lane >> 4;
  const int pcol = ((gi ^ ((lane >> 1) & 3)) << 3);
  const int nt = K >> 5;

  auto stage = [&](int t, int buf) {
    h16* lbase = lds + buf*BUF + lo;
    const long k0 = (long)t << 5;
    #pragma unroll
    for (int g = 0; g < 4; ++g)
      gload16(gp + g0[g] + k0, lbase + (g*16)*SLDA);
  };

  stage(0, 0);
  __syncthreads();
  int cur = 0;
  for (int t = 0; t < nt; ++t) {
    if (t + 1 < nt) stage(t + 1, cur ^ 1);
    h16* base = lds + cur*BUF;
    h16* sA_ = base;
    h16* sB_ = base + 256*SLDA;
    h16x8 b_[4];
    #pragma unroll
    for (int j = 0; j < 4; ++j)
      b_[j] = *(const h16x8*)(sB_ + (wc + j*16 + fr)*SLDA + pcol);
    __builtin_amdgcn_s_setprio(1);
    #pragma unroll
    for (int i = 0; i < 8; ++i) {
      h16x8 a_ = *(const h16x8*)(sA_ + (wr + i*16 + fr)*SLDA + pcol);
      #pragma unroll
      for (int j = 0; j < 4; ++j)
        acc[i][j] = MFMA16(a_, b_[j], acc[i][j]);
    }
    __builtin_amdgcn_s_setprio(0);
    __syncthreads();
    cur ^= 1;
  }
}

// ---------------------------------------------------------------------------
// FUSED prep kernel #1 (BEFORE qkv): counts/cursor zero + input split +
// w3/wo split. Block-range branching; all ranges exact multiples of 256.
// ---------------------------------------------------------------------------
__device__ __forceinline__ void d_split2(const float* __restrict__ a,
                                         h16* __restrict__ H, h16* __restrict__ L,
                                         int i) {
  float4 v = ((const float4*)a)[i];
  float vv[4] = {v.x, v.y, v.z, v.w};
  h16x4 hv, lv;
  #pragma unroll
  for (int q = 0; q < 4; ++q) {
    float x = vv[q] * 64.0f;
    h16 h = (h16)x;
    hv[q] = h;
    lv[q] = (h16)(x - (float)h);
  }
  ((h16x4*)H)[i] = hv;
  ((h16x4*)L)[i] = lv;
}

__global__ __launch_bounds__(256) void k_prep(
    const float* __restrict__ src, const float* __restrict__ pos,
    const float* __restrict__ w3,  const float* __restrict__ wo,
    h16* __restrict__ qkH, h16* __restrict__ qkL,
    h16* __restrict__ sH,  h16* __restrict__ sL,
    h16* __restrict__ W3H, h16* __restrict__ W3L,
    h16* __restrict__ WOH, h16* __restrict__ WOL,
    int* __restrict__ cnt)
{
  const int b = blockIdx.x, tid = threadIdx.x;
  if (b == 0 && tid < 8) cnt[tid] = 0;      // counts[4] + cursor[4]
  if (b < NB_IN) {
    int i = b*256 + tid;
    float4 s = ((const float4*)src)[i];
    float4 p = ((const float4*)pos)[i];
    float sv[4] = {s.x, s.y, s.z, s.w};
    float qv[4] = {s.x+p.x, s.y+p.y, s.z+p.z, s.w+p.w};
    h16x4 sh, sl, qh, ql;
    #pragma unroll
    for (int q = 0; q < 4; ++q) {
      float xs = sv[q] * 16.0f; h16 hs = (h16)xs;
      sh[q] = hs; sl[q] = (h16)(xs - (float)hs);
      float xq = qv[q] * 16.0f; h16 hq = (h16)xq;
      qh[q] = hq; ql[q] = (h16)(xq - (float)hq);
    }
    ((h16x4*)sH)[i] = sh; ((h16x4*)sL)[i] = sl;
    ((h16x4*)qkH)[i] = qh; ((h16x4*)qkL)[i] = ql;
  } else if (b < NB_IN + NB_W3) {
    d_split2(w3, W3H, W3L, (b - NB_IN)*256 + tid);
  } else {
    d_split2(wo, WOH, WOL, (b - NB_IN - NB_W3)*256 + tid);
  }
}

// ---------------------------------------------------------------------------
// FUSED prep kernel #2 (AFTER attn — W1H/W2H alias the dead KL plane!):
// w1 + w2 -> f16.
// ---------------------------------------------------------------------------
__global__ __launch_bounds__(256) void k_prepw(
    const float* __restrict__ w1, const float* __restrict__ w2,
    h16* __restrict__ W1H, h16* __restrict__ W2H)
{
  const int b = blockIdx.x, tid = threadIdx.x;
  const float* a; h16* H; int i;
  if (b < NB_W1) { a = w1; H = W1H; i = b*256 + tid; }
  else           { a = w2; H = W2H; i = (b - NB_W1)*256 + tid; }
  float4 v = ((const float4*)a)[i];
  h16x4 hv;
  hv[0] = (h16)(v.x*64.0f); hv[1] = (h16)(v.y*64.0f);
  hv[2] = (h16)(v.z*64.0f); hv[3] = (h16)(v.w*64.0f);
  ((h16x4*)H)[i] = hv;
}

// ---------------------------------------------------------------------------
// QKV projection (128x256 split dbuf, m-fast XCD mapping; grid 768)
// V-lo no longer stored (attn dropped V-lo; buffer dead).
// ---------------------------------------------------------------------------
__global__ __launch_bounds__(512) void k_qkv(
    const h16* __restrict__ qkh, const h16* __restrict__ qkl,
    const h16* __restrict__ sh,  const h16* __restrict__ sl,
    const h16* __restrict__ Wh,  const h16* __restrict__ Wl, const float* __restrict__ bias,
    h16* __restrict__ Qh, h16* __restrict__ Ql, h16* __restrict__ Kh, h16* __restrict__ Kl,
    h16* __restrict__ Vh)
{
  __shared__ h16 lds[2*768*SLDA];
  const int bid = blockIdx.x;
  const int xcd = bid & 7, loc = bid >> 3;
  const int m0 = (xcd*8 + (loc & 7)) * 128;
  const int n0 = (loc >> 3) * 256;
  const bool isV = (n0 >= 2048);
  f32x4 acc[4][4] = {};
  gemm128x256_core(isV ? sh : qkh, isV ? sl : qkl, Wh, Wl,
                   1024, 1024, 1024, m0, n0, acc, lds);
  EPI_128x256;
  if (!isV) {
    const bool isK = (n0 >= 1024);
    h16* Hd = isK ? Kh : Qh;
    h16* Ld = isK ? Kl : Ql;
    #pragma unroll
    for (int i = 0; i < 4; ++i)
      #pragma unroll
      for (int j = 0; j < 4; ++j)
        #pragma unroll
        for (int r = 0; r < 4; ++r) {
          int row = m0 + wr + i*16 + rb + r;
          int col = n0 + wc + j*16 + fr;
          float c = acc[i][j][r] * (1.0f/1024.0f) + bias[col];
          int b = row >> 10, s = row & 1023;
          int cc = col & 1023, h = cc >> 6, d = cc & 63;
          long bh = (long)b*NH + h;
          store_split(Hd, Ld, (bh*SEQ + s)*HD + d, c * 16.0f);
        }
  } else {
    #pragma unroll
    for (int i = 0; i < 4; ++i)
      #pragma unroll
      for (int j = 0; j < 4; ++j) {
        int row0 = m0 + wr + i*16 + rb;
        int col  = n0 + wc + j*16 + fr;
        int cc = col & 1023, h = cc >> 6, d = cc & 63;
        float bcol = bias[col];
        h16x4 hv;
        #pragma unroll
        for (int r = 0; r < 4; ++r) {
          float cs = (acc[i][j][r] * (1.0f/1024.0f) + bcol) * 16.0f;
          hv[r] = (h16)cs;
        }
        int b = row0 >> 10, s0 = row0 & 1023;
        long base = ((long)(b*NH + h)*HD + d)*SEQ + s0;
        *(h16x4*)(Vh + base) = hv;
      }
  }
}

// ---------------------------------------------------------------------------
// Fused flash attention, QB=128, dbuf K/V (ONE barrier per tile) + T14 + T13.
// ROUND 25: 3 LDS planes (Kh,Kl,Vh; FLD=68 -> 52KB dbuf -> 3 blocks/CU);
// P stored hi-only (pa), V hi-only -> o2 accumulator REMOVED.
// PV: 8 MFMA/iter (was 24); shfl 16/iter (was 32).
// ---------------------------------------------------------------------------
__global__ __launch_bounds__(512) void k_attn(
    const h16* __restrict__ Qh, const h16* __restrict__ Ql,
    const h16* __restrict__ Kh, const h16* __restrict__ Kl,
    const h16* __restrict__ Vh,
    h16* __restrict__ Oh, h16* __restrict__ Ol)
{
  constexpr int BUFA = 3*64*FLD;        // 13,056 h16 per buffer
  __shared__ h16 lds[2*BUFA];           // 52,224 B -> 3 blocks/CU
  const int bid = blockIdx.x;                  // 0..1023
  const int swz = (bid & 7) * 128 + (bid >> 3);
  const int bh = swz >> 3;
  const int q0 = (swz & 7) * QB;
  const int tid = threadIdx.x, lane = tid & 63, w = tid >> 6;
  const int fr = lane & 15, hg = lane >> 4;
  const int kg = hg << 3;
  const long qbase = ((long)bh*SEQ + q0 + w*16 + fr) * HD;
  h16x8 qh[2], ql[2];
  qh[0] = *(const h16x8*)(Qh + qbase + kg);
  qh[1] = *(const h16x8*)(Qh + qbase + 32 + kg);
  ql[0] = *(const h16x8*)(Ql + qbase + kg);
  ql[1] = *(const h16x8*)(Ql + qbase + 32 + kg);
  f32x4 o1[4] = {};
  float mrow = -3.0e38f, lrow = 0.f;
  const int srow = tid >> 3, skc = (tid & 7) << 3;
  const long kbase = ((long)bh*SEQ + srow) * HD + skc;
  const long vbase = ((long)bh*HD + srow) * SEQ + skc;
  const int srcA = fr + ((hg & 1) << 5);
  const int srcB = srcA + 16;
  uint4 rKh, rKl, rVh;
  auto loadt = [&](int kt) {
    const long ka = kbase + (long)(kt*64)*HD;
    rKh = *(const uint4*)(Kh + ka);
    rKl = *(const uint4*)(Kl + ka);
    rVh = *(const uint4*)(Vh + vbase + kt*64);
  };
  auto wbuf = [&](int buf) {
    h16* nb = lds + buf*BUFA;
    *(uint4*)(nb + srow*FLD + skc)            = rKh;
    *(uint4*)(nb + 64*FLD + srow*FLD + skc)   = rKl;
    *(uint4*)(nb + 2*64*FLD + srow*FLD + skc) = rVh;
  };
  loadt(0);
  wbuf(0);
  int cur = 0;
  for (int kt = 0; kt < NCHUNK; ++kt) {
    __syncthreads();                     // publishes buf[cur]; retires prev reads
    if (kt + 1 < NCHUNK) loadt(kt + 1);  // global->reg, hides under compute
    h16* base = lds + cur*BUFA;
    h16* sKh = base;
    h16* sKl = base + 64*FLD;
    h16* sVh = base + 2*64*FLD;
    f32x4 s1[4] = {}, s2[4] = {};
    __builtin_amdgcn_s_setprio(1);
    #pragma unroll
    for (int ks = 0; ks < 2; ++ks)
      #pragma unroll
      for (int j = 0; j < 4; ++j) {
        h16x8 kh = *(const h16x8*)(sKh + (j*16 + fr)*FLD + ks*32 + kg);
        h16x8 kl = *(const h16x8*)(sKl + (j*16 + fr)*FLD + ks*32 + kg);
        s1[j] = MFMA16(kh, qh[ks], s1[j]);
        s2[j] = MFMA16(kh, ql[ks], s2[j]);
        s2[j] = MFMA16(kl, qh[ks], s2[j]);
      }
    __builtin_amdgcn_s_setprio(0);
    float p[4][4];
    float tmax = -3.0e38f;
    #pragma unroll
    for (int j = 0; j < 4; ++j)
      #pragma unroll
      for (int r = 0; r < 4; ++r) {
        float sc = (s1[j][r] + s2[j][r]) * (0.125f/256.0f);
        p[j][r] = sc;
        tmax = fmaxf(tmax, sc);
      }
    tmax = fmaxf(tmax, __shfl_xor(tmax, 16));
    tmax = fmaxf(tmax, __shfl_xor(tmax, 32));
    float mn;
    const bool defer = (__all(tmax - mrow <= 4.0f) != 0);
    float sclf;
    if (defer) {
      mn = mrow;
      sclf = 1.0f;
    } else {
      mn = fmaxf(mrow, tmax);
      sclf = __expf(mrow - mn);
      mrow = mn;
    }
    float psum = 0.f;
    #pragma unroll
    for (int j = 0; j < 4; ++j)
      #pragma unroll
      for (int r = 0; r < 4; ++r) { float e = __expf(p[j][r] - mn); p[j][r] = e; psum += e; }
    psum += __shfl_xor(psum, 16);
    psum += __shfl_xor(psum, 32);
    lrow = lrow*sclf + psum;
    if (!defer) {
      #pragma unroll
      for (int r = 0; r < 4; ++r) {
        float sq = __shfl(sclf, hg*4 + r);
        #pragma unroll
        for (int jd = 0; jd < 4; ++jd) o1[jd][r] *= sq;
      }
    }
    u32 hp[4][2];
    #pragma unroll
    for (int j = 0; j < 4; ++j)
      #pragma unroll
      for (int rp = 0; rp < 2; ++rp)
        hp[j][rp] = pk2w(p[j][2*rp] * 512.0f, p[j][2*rp+1] * 512.0f);
    #pragma unroll
    for (int ks = 0; ks < 2; ++ks) {
      const int j0 = 2*ks, j1 = 2*ks + 1;
      u32 hA0 = (u32)__shfl((int)hp[j0][0], srcA), hA1 = (u32)__shfl((int)hp[j0][1], srcA);
      u32 hB0 = (u32)__shfl((int)hp[j0][0], srcB), hB1 = (u32)__shfl((int)hp[j0][1], srcB);
      u32 hC0 = (u32)__shfl((int)hp[j1][0], srcA), hC1 = (u32)__shfl((int)hp[j1][1], srcA);
      u32 hD0 = (u32)__shfl((int)hp[j1][0], srcB), hD1 = (u32)__shfl((int)hp[j1][1], srcB);
      const bool hij = (hg & 2) != 0;
      union { u32 w[4]; h16x8 v; } pa;
      pa.w[0] = hij ? hC0 : hA0;  pa.w[1] = hij ? hC1 : hA1;
      pa.w[2] = hij ? hD0 : hB0;  pa.w[3] = hij ? hD1 : hB1;
      __builtin_amdgcn_s_setprio(1);
      #pragma unroll
      for (int jd = 0; jd < 4; ++jd) {
        h16x8 vh = *(const h16x8*)(sVh + (jd*16 + fr)*FLD + ks*32 + kg);
        o1[jd] = MFMA16(pa.v, vh, o1[jd]);
      }
      __builtin_amdgcn_s_setprio(0);
    }
    if (kt + 1 < NCHUNK) wbuf(cur ^ 1);  // write next tile; published by next barrier
    cur ^= 1;
  }
  float lq[4];
  #pragma unroll
  for (int r = 0; r < 4; ++r) lq[r] = __shfl(lrow, hg*4 + r);
  const int b = bh >> 4, h = bh & 15;
  #pragma unroll
  for (int jd = 0; jd < 4; ++jd)
    #pragma unroll
    for (int r = 0; r < 4; ++r) {
      int qrow = q0 + w*16 + hg*4 + r;
      int d = jd*16 + fr;
      float ov = o1[jd][r] / (512.0f*16.0f*lq[r]);
      store_split(Oh, Ol, ((long)b*SEQ + qrow)*DM + h*HD + d, ov*16.0f);
    }
}

// out_proj (128x256 split dbuf, m-fast XCD mapping; grid 256)
__global__ __launch_bounds__(512) void k_out(
    const h16* __restrict__ Oh, const h16* __restrict__ Ol,
    const h16* __restrict__ Wh, const h16* __restrict__ Wl,
    const float* __restrict__ bias, float* __restrict__ attn)
{
  __shared__ h16 lds[2*768*SLDA];
  const int bid = blockIdx.x;
  const int xcd = bid & 7, loc = bid >> 3;
  const int m0 = (xcd*8 + (loc & 7)) * 128;
  const int n0 = (loc >> 3) * 256;
  f32x4 acc[4][4] = {};
  gemm128x256_core(Oh, Ol, Wh, Wl, 1024, 1024, 1024, m0, n0, acc, lds);
  EPI_128x256;
  #pragma unroll
  for (int i = 0; i < 4; ++i)
    #pragma unroll
    for (int j = 0; j < 4; ++j)
      #pragma unroll
      for (int r = 0; r < 4; ++r) {
        int row = m0 + wr + i*16 + rb + r;
        int col = n0 + wc + j*16 + fr;
        attn[(long)row*DM + col] = acc[i][j][r] * (1.0f/1024.0f) + bias[col];
      }
}

// ---------------------------------------------------------------------------
// threefry2x32 (key=[0,42]) -> gumbel -> argmax. VERIFIED round 5 — DO NOT TOUCH.
// ---------------------------------------------------------------------------
__device__ __forceinline__ void threefry(u32 x0, u32 x1, u32& y0, u32& y1) {
  const u32 ks0 = 0u, ks1 = 42u, ks2 = 0x1BD11BDAu ^ 42u;
  x0 += ks0; x1 += ks1;
  #define TF_R(r) { x0 += x1; x1 = (x1 << r) | (x1 >> (32 - r)); x1 ^= x0; }
  TF_R(13) TF_R(15) TF_R(26) TF_R(6)  x0 += ks1; x1 += ks2 + 1u;
  TF_R(17) TF_R(29) TF_R(16) TF_R(24) x0 += ks2; x1 += ks0 + 2u;
  TF_R(13) TF_R(15) TF_R(26) TF_R(6)  x0 += ks0; x1 += ks1 + 3u;
  TF_R(17) TF_R(29) TF_R(16) TF_R(24) x0 += ks1; x1 += ks2 + 4u;
  TF_R(13) TF_R(15) TF_R(26) TF_R(6)  x0 += ks2; x1 += ks0 + 5u;
  #undef TF_R
  y0 = x0; y1 = x1;
}

__device__ __forceinline__ float gumbel_from(u32 bits) {
  float f = __uint_as_float((bits >> 9) | 0x3F800000u) - 1.0f;
  float u = (f > 0.0f) ? f : 1.17549435e-38f;
  float nl = (float)(-log((double)u));
  return -(float)log((double)nl);
}

// LN1 + GATE fused
__global__ __launch_bounds__(256) void k_ln1g(
    const float* __restrict__ A, const float* __restrict__ Badd,
    const float* __restrict__ g, const float* __restrict__ be,
    const float* __restrict__ gw, const float* __restrict__ gb,
    float* __restrict__ xout, h16* __restrict__ xh,
    int* __restrict__ chosen, int* __restrict__ counts)
{
  int wave = threadIdx.x >> 6, lane = threadIdx.x & 63;
  long row = (long)blockIdx.x*4 + wave;
  const float* ar = A + row*DM; const float* br = Badd + row*DM;
  float v[16]; float s = 0.0f;
  #pragma unroll
  for (int p = 0; p < 4; ++p) {
    int d = p*256 + lane*4;
    float4 a = *(const float4*)(ar + d);
    float4 b = *(const float4*)(br + d);
    float t0=a.x+b.x, t1=a.y+b.y, t2=a.z+b.z, t3=a.w+b.w;
    v[4*p+0]=t0; v[4*p+1]=t1; v[4*p+2]=t2; v[4*p+3]=t3;
    s += t0+t1+t2+t3;
  }
  s = wave_sum(s);
  float m = s * (1.0f/1024.0f);
  float q = 0.0f;
  #pragma unroll
  for (int i = 0; i < 16; ++i) { float dd = v[i]-m; q += dd*dd; }
  q = wave_sum(q);
  float rs = (float)(1.0 / sqrt((double)(q * (1.0f/1024.0f) + 1e-5f)));
  float pe[4] = {0.f, 0.f, 0.f, 0.f};
  #pragma unroll
  for (int p = 0; p < 4; ++p) {
    int d = p*256 + lane*4;
    float4 gv = *(const float4*)(g + d);
    float4 bv = *(const float4*)(be + d);
    float y0 = (v[4*p+0]-m)*rs*gv.x + bv.x;
    float y1 = (v[4*p+1]-m)*rs*gv.y + bv.y;
    float y2 = (v[4*p+2]-m)*rs*gv.z + bv.z;
    float y3 = (v[4*p+3]-m)*rs*gv.w + bv.w;
    float4 o = {y0,y1,y2,y3};
    *(float4*)(xout + row*DM + d) = o;
    h16x4 hv; hv[0]=(h16)(y0*16.f); hv[1]=(h16)(y1*16.f);
    hv[2]=(h16)(y2*16.f); hv[3]=(h16)(y3*16.f);
    *(h16x4*)(xh + row*DM + d) = hv;
    #pragma unroll
    for (int e = 0; e < 4; ++e) {
      float4 w4 = *(const float4*)(gw + e*DM + d);
      pe[e] += y0*w4.x + y1*w4.y + y2*w4.z + y3*w4.w;
    }
  }
  #pragma unroll
  for (int e = 0; e < 4; ++e) pe[e] = wave_sum(pe[e]);
  if (lane == 0) {
    float best = -3.0e38f; int arg = 0;
    #pragma unroll
    for (int e = 0; e < 4; ++e) {
      float logit = pe[e] + gb[e];
      u32 j = (u32)(4*row + e);
      u32 y0, y1;
      threefry(0u, j, y0, y1);
      float vv = gumbel_from(y0 ^ y1) + logit;
      if (vv > best) { best = vv; arg = e; }
    }
    chosen[(int)row] = arg;
    atomicAdd(&counts[arg], 1);
  }
}

// LayerNorm of (A + Badd) — LN2
__global__ __launch_bounds__(256) void k_ln(
    const float* __restrict__ A, const float* __restrict__ Badd,
    const float* __restrict__ g, const float* __restrict__ be,
    float* __restrict__ dout)
{
  int wave = threadIdx.x >> 6, lane = threadIdx.x & 63;
  long row = (long)blockIdx.x*4 + wave;
  const float* ar = A + row*DM; const float* br = Badd + row*DM;
  float v[16]; float s = 0.0f;
  #pragma unroll
  for (int p = 0; p < 4; ++p) {
    int d = p*256 + lane*4;
    float4 a = *(const float4*)(ar + d);
    float4 b = *(const float4*)(br + d);
    float t0=a.x+b.x, t1=a.y+b.y, t2=a.z+b.z, t3=a.w+b.w;
    v[4*p+0]=t0; v[4*p+1]=t1; v[4*p+2]=t2; v[4*p+3]=t3;
    s += t0+t1+t2+t3;
  }
  s = wave_sum(s);
  float m = s * (1.0f/1024.0f);
  float q = 0.0f;
  #pragma unroll
  for (int i = 0; i < 16; ++i) { float dd = v[i]-m; q += dd*dd; }
  q = wave_sum(q);
  float rs = (float)(1.0 / sqrt((double)(q * (1.0f/1024.0f) + 1e-5f)));
  #pragma unroll
  for (int p = 0; p < 4; ++p) {
    int d = p*256 + lane*4;
    float4 gv = *(const float4*)(g + d);
    float4 bv = *(const float4*)(be + d);
    float y0 = (v[4*p+0]-m)*rs*gv.x + bv.x;
    float y1 = (v[4*p+1]-m)*rs*gv.y + bv.y;
    float y2 = (v[4*p+2]-m)*rs*gv.z + bv.z;
    float y3 = (v[4*p+3]-m)*rs*gv.w + bv.w;
    float4 o = {y0,y1,y2,y3};
    *(float4*)(dout + row*DM + d) = o;
  }
}

// ---------------------------------------------------------------------------
// FUSED bucketing: per-thread local prefix over 4 experts. Grid 40 x 256.
// ---------------------------------------------------------------------------
__global__ __launch_bounds__(256) void k_bucket(
    const int* __restrict__ chosen, const int* __restrict__ counts,
    int* __restrict__ cursor, int* __restrict__ eoff, int* __restrict__ plist)
{
  const int tid = threadIdx.x, b = blockIdx.x;
  const int c0 = counts[0], c1 = counts[1], c2 = counts[2], c3 = counts[3];
  const int p0 = (c0+255)&~255, p1 = (c1+255)&~255, p2 = (c2+255)&~255, p3 = (c3+255)&~255;
  const int o1 = p0, o2 = p0+p1, o3 = p0+p1+p2, end = o3+p3;
  if (b == 0 && tid < 4)
    eoff[tid] = (tid==0) ? 0 : (tid==1) ? o1 : (tid==2) ? o2 : o3;
  if (b < 32) {
    int t = b*256 + tid;
    int e = chosen[t];
    int slot = atomicAdd(&cursor[e], 1);
    int base = (e==0) ? 0 : (e==1) ? o1 : (e==2) ? o2 : o3;
    plist[base + slot] = t;
  } else if (b < 36) {
    int e = b - 32;
    int ce = (e==0) ? c0 : (e==1) ? c1 : (e==2) ? c2 : c3;
    int base = ((e==0) ? 0 : (e==1) ? o1 : (e==2) ? o2 : o3) + ce;
    int pad = (((ce+255)&~255) - ce);
    if (tid < pad) plist[base + tid] = -1;
  } else {
    int idx = end + (b-36)*256 + tid;
    if (idx < NPOS) plist[idx] = -1;
  }
}

// MoE layer 1 (gathered rows, 256^2 f16 dbuf core)
__global__ __launch_bounds__(512, 2) void k_e1(
    const h16* __restrict__ Xh, const h16* __restrict__ W1, const float* __restrict__ b1,
    const int* __restrict__ plist, const int* __restrict__ eoff, h16* __restrict__ Hh)
{
  __shared__ h16 lds[2*2*256*SLDA];
  const int n0 = blockIdx.x*256, m0 = blockIdx.y*256;
  const int e = (m0 >= eoff[1]) + (m0 >= eoff[2]) + (m0 >= eoff[3]);
  f32x4 acc[8][4] = {};
  hgemm256_core<true>(Xh, W1 + (long)e*DFE*DM, 1024, 1024, 1024, m0, n0, plist, acc, lds);
  EPI_256;
  #pragma unroll
  for (int i = 0; i < 8; ++i)
    #pragma unroll
    for (int j = 0; j < 4; ++j)
      #pragma unroll
      for (int r = 0; r < 4; ++r) {
        int row = m0 + wr + i*16 + rb + r;
        int col = n0 + wc + j*16 + fr;
        float c = acc[i][j][r] * (1.0f/1024.0f) + b1[e*DFE + col];
        c = fmaxf(c, 0.0f);
        Hh[(long)row*DFE + col] = (h16)(c * 16.0f);
      }
}

// MoE layer 2 (bucket rows, 256^2 f16 dbuf core, scatter out)
__global__ __launch_bounds__(512, 2) void k_e2(
    const h16* __restrict__ Hh, const h16* __restrict__ W2, const float* __restrict__ b2,
    const int* __restrict__ plist, const int* __restrict__ eoff, float* __restrict__ y)
{
  __shared__ h16 lds[2*2*256*SLDA];
  const int n0 = blockIdx.x*256, m0 = blockIdx.y*256;
  const int e = (m0 >= eoff[1]) + (m0 >= eoff[2]) + (m0 >= eoff[3]);
  f32x4 acc[8][4] = {};
  hgemm256_core<false>(Hh, W2 + (long)e*DM*DFE, 1024, DFE, DFE, m0, n0, nullptr, acc, lds);
  EPI_256;
  #pragma unroll
  for (int i = 0; i < 8; ++i)
    #pragma unroll
    for (int j = 0; j < 4; ++j)
      #pragma unroll
      for (int r = 0; r < 4; ++r) {
        int row = m0 + wr + i*16 + rb + r;
        int col = n0 + wc + j*16 + fr;
        int t = plist[row];
        if (t >= 0)
          y[(long)t*DM + col] = acc[i][j][r] * (1.0f/1024.0f) + b2[e*DM + col];
      }
}

// ---------------------------------------------------------------------------
extern "C" void kernel_launch(void* const* d_in, const int* in_sizes, int n_in,
                              void* d_out, int out_size, void* d_ws, size_t ws_size,
                              hipStream_t stream) {
  const float* src = (const float*)d_in[0];
  const float* pos = (const float*)d_in[1];
  const float* w3  = (const float*)d_in[2];
  const float* b3  = (const float*)d_in[3];
  const float* wo  = (const float*)d_in[4];
  const float* bo  = (const float*)d_in[5];
  const float* gw  = (const float*)d_in[6];
  const float* gb  = (const float*)d_in[7];
  const float* w1  = (const float*)d_in[8];
  const float* b1  = (const float*)d_in[9];
  const float* w2  = (const float*)d_in[10];
  const float* b2  = (const float*)d_in[11];
  const float* g1  = (const float*)d_in[12];
  const float* be1 = (const float*)d_in[13];
  const float* g2  = (const float*)d_in[14];
  const float* be2 = (const float*)d_in[15];
  float* out = (float*)d_out;
  char* ws = (char*)d_ws;
  if (ws_size < WS_NEEDED) return;

  auto H = [&](size_t off) { return (h16*)(ws + off); };
  auto F = [&](size_t off) { return (float*)(ws + off); };
  auto I = [&](size_t off) { return (int*)(ws + off); };

  // 1) zero + input/w3/wo conversion (W1/W2 must wait: they alias KL)
  k_prep<<<dim3(NB_PREP), 256, 0, stream>>>(
      src, pos, w3, wo,
      H(OFF_QKH), H(OFF_QKL), H(OFF_SRCH), H(OFF_SRCL),
      H(OFF_W3H), H(OFF_W3L), H(OFF_WOH), H(OFF_WOL), I(OFF_COUNTS));

  // 2) QKV projection (128x256 dbuf, grid 768 = 3 full rounds)
  k_qkv<<<dim3(768), 512, 0, stream>>>(
      H(OFF_QKH), H(OFF_QKL), H(OFF_SRCH), H(OFF_SRCL), H(OFF_W3H), H(OFF_W3L), b3,
      H(OFF_QH), H(OFF_QL), H(OFF_KH), H(OFF_KL), H(OFF_VH));

  // 3) fused flash attention (QB=128, dbuf K/V, T14+T13, hi-only P/V)
  k_attn<<<dim3(NBH*(SEQ/QB)), 512, 0, stream>>>(
      H(OFF_QH), H(OFF_QL), H(OFF_KH), H(OFF_KL), H(OFF_VH),
      H(OFF_OH), H(OFF_OL));

  // 4) w1/w2 -> f16 (KL is dead now; W1H/W2H occupy its plane)
  k_prepw<<<dim3(NB_PREPW), 256, 0, stream>>>(w1, w2, H(OFF_W1H), H(OFF_W2H));

  // 5) out projection (grid 256 = 1 full round)
  k_out<<<dim3(256), 512, 0, stream>>>(
      H(OFF_OH), H(OFF_OL), H(OFF_WOH), H(OFF_WOL), bo, F(OFF_ATT));

  // 6) LN1 + gate
  k_ln1g<<<BS/4, 256, 0, stream>>>(src, F(OFF_ATT), g1, be1, gw, gb,
      F(OFF_X), H(OFF_XH), I(OFF_CHOSEN), I(OFF_COUNTS));

  // 7) bucketing in ONE launch (offsets+fill+scatter)
  k_bucket<<<dim3(40), 256, 0, stream>>>(
      I(OFF_CHOSEN), I(OFF_COUNTS), I(OFF_CURSOR), I(OFF_EOFF), I(OFF_PLIST));

  // 8-9) MoE (256^2 f16 dbuf cores)
  k_e1<<<dim3(DFE/256, NPOS/256), 512, 0, stream>>>(
      H(OFF_XH), H(OFF_W1H), b1, I(OFF_PLIST), I(OFF_EOFF), H(OFF_HH));
  k_e2<<<dim3(DM/256, NPOS/256), 512, 0, stream>>>(
      H(OFF_HH), H(OFF_W2H), b2, I(OFF_PLIST), I(OFF_EOFF), F(OFF_Y));

  // 10) final LN2 -> output
  k_ln<<<BS/4, 256, 0, stream>>>(F(OFF_X), F(OFF_Y), g2, be2, out);
}

// Round 26
// 601.230 us; speedup vs baseline: 1.4714x; 1.4714x over previous
//
#include <hip/hip_runtime.h>
#include <cstdint>
#include <cstddef>

// ---------------------------------------------------------------------------
// TransformerEncoderLayer on MI355X (gfx950).
// Split format: x ~ (hi + lo)/s, lo unscaled residual; 3 MFMAs into ONE acc.
// QKV/out_proj: 128x256 split dbuf core (grids 768/256, verified round 21).
// MoE: 256x256 f16 dbuf core. Gate fused in LN1.
// Attention: fused flash QB=128, dbuf K/V + T14 + T13; 3 LDS planes
// (Kh,Kl,Vh), hi-only P/V (PV 8 MFMA/iter). ROUND 26: FLD back to 72 —
// FLD MUST be a multiple of 8 h16 (16B row alignment for ds_*_b128);
// FLD=68 put odd rows 8B-misaligned -> LDS slow path (408us, round 25).
// Launches: 10. Gate RNG: threefry b1^b2 (VERIFIED round 5 — DO NOT TOUCH).
// ---------------------------------------------------------------------------

typedef _Float16 h16;
typedef h16 h16x8 __attribute__((ext_vector_type(8)));
typedef h16 h16x4 __attribute__((ext_vector_type(4)));
typedef __fp16 fp16x2 __attribute__((ext_vector_type(2)));
typedef float f32x4 __attribute__((ext_vector_type(4)));
typedef uint32_t u32;

#define DM 1024
#define NH 16
#define HD 64
#define SEQ 1024
#define BB 8
#define BS (BB*SEQ)
#define NBH (BB*NH)
#define NE 4
#define DFE 1024
#define QB 128           /* q-rows per attention block (8 waves x 16) */
#define NCHUNK 16        /* KV tiles of 64 */
#define SLDA 32
#define FLD 72           /* MUST be multiple of 8 (16B-aligned rows) */
#define NPOS 9216

#define MFMA16(a,b,c) __builtin_amdgcn_mfma_f32_16x16x32_f16(a,b,c,0,0,0)

// ---- workspace layout (bytes). E = one h16 plane of [8192][1024]. ----
// ALIASING DISCIPLINE: 8E..9E = KL during attention, W1H/W2H after (k_prepw
// MUST launch after k_attn). 5E..8E = Q/K-hi during attn, X/XH after.
static constexpr size_t E = (size_t)BS*DM*2;
static constexpr size_t OFF_QKH = 0;
static constexpr size_t OFF_QKL = E;
static constexpr size_t OFF_SRCH= 2*E;
static constexpr size_t OFF_SRCL= 3*E;
static constexpr size_t OFF_W3H = 4*E;
static constexpr size_t OFF_W3L = 4*E + (size_t)3*DM*DM*2;
static constexpr size_t OFF_WOH = 4*E + (size_t)6*DM*DM*2;
static constexpr size_t OFF_WOL = 4*E + (size_t)7*DM*DM*2;
static constexpr size_t OFF_QH  = 5*E;
static constexpr size_t OFF_QL  = 6*E;
static constexpr size_t OFF_KH  = 7*E;
static constexpr size_t OFF_KL  = 8*E;
static constexpr size_t OFF_VH  = 9*E;
static constexpr size_t OFF_OH  = 0;
static constexpr size_t OFF_OL  = E;
static constexpr size_t OFF_ATT = 2*E;
static constexpr size_t OFF_X   = 5*E;
static constexpr size_t OFF_XH  = 7*E;
static constexpr size_t OFF_W1H = 8*E;
static constexpr size_t OFF_W2H = 8*E + (size_t)NE*DFE*DM*2;
static constexpr size_t OFF_HH  = 9*E;
static constexpr size_t OFF_Y   = 11*E;
static constexpr size_t OFF_CHOSEN = 13*E;
static constexpr size_t OFF_COUNTS = 13*E + 32768;
static constexpr size_t OFF_CURSOR = OFF_COUNTS + 16;
static constexpr size_t OFF_EOFF   = OFF_CURSOR + 16;
static constexpr size_t OFF_PLIST  = OFF_EOFF + 16;
static constexpr size_t WS_NEEDED  = OFF_PLIST + (size_t)NPOS*4;

// prep kernel block ranges (all exact, 256 thr, 4 floats/thread)
#define NB_IN  8192   /* BS*DM/4/256      */
#define NB_W3  3072   /* 3*DM*DM/4/256    */
#define NB_WO  1024   /* DM*DM/4/256      */
#define NB_PREP (NB_IN+NB_W3+NB_WO)          /* 12288 */
#define NB_W1  4096   /* NE*DFE*DM/4/256  */
#define NB_PREPW (2*NB_W1)                   /* 8192  */

// ---------------------------------------------------------------------------
__device__ __forceinline__ void store_split(h16* H, h16* L, size_t idx, float v) {
  h16 h = (h16)v;
  H[idx] = h;
  L[idx] = (h16)(v - (float)h);
}

__device__ __forceinline__ float wave_sum(float v) {
  #pragma unroll
  for (int o = 32; o; o >>= 1) v += __shfl_xor(v, o);
  return v;
}

__device__ __forceinline__ u32 pk2w(float a, float b) {
  union { fp16x2 h; u32 w; } u;
  u.h = __builtin_amdgcn_cvt_pkrtz(a, b);
  return u.w;
}

__device__ __forceinline__ void gload16(const void* g, void* l) {
  __builtin_amdgcn_global_load_lds(
      (const __attribute__((address_space(1))) u32*)g,
      (__attribute__((address_space(3))) u32*)l, 16, 0, 0);
}

// ---------------------------------------------------------------------------
// 128(M)x256(N) split-f16 MERGED-ACC core, DOUBLE-BUFFERED (verified r21).
// ---------------------------------------------------------------------------
__device__ __forceinline__ void gemm128x256_core(
    const h16* __restrict__ Ah, const h16* __restrict__ Al,
    const h16* __restrict__ Bh, const h16* __restrict__ Bl,
    int K, int lda, int ldb, int m0, int n0,
    f32x4 (&acc)[4][4], h16* lds)
{
  constexpr int ROWS = 768;
  constexpr int BUF = ROWS*SLDA;
  const int tid = threadIdx.x, lane = tid & 63, wid = tid >> 6;
  const int wr = (wid >> 2) * 64, wc = (wid & 3) * 64;
  const int lr16 = lane >> 2, lgrp = lane & 3;
  const int sw = (lr16 >> 1) & 3;
  const int colo = (lgrp ^ sw) << 3;
  const h16* gptr[6];
  long gaddr[6];
  int ldsoff[6];
  #pragma unroll
  for (int g = 0; g < 6; ++g) {
    const int R0 = wid*96 + g*16;
    const h16* gp; int prow, ld, base0;
    if (R0 < 128)      { gp = Ah; prow = R0;       ld = lda; base0 = m0; }
    else if (R0 < 256) { gp = Al; prow = R0 - 128; ld = lda; base0 = m0; }
    else if (R0 < 512) { gp = Bh; prow = R0 - 256; ld = ldb; base0 = n0; }
    else               { gp = Bl; prow = R0 - 512; ld = ldb; base0 = n0; }
    gptr[g]   = gp;
    gaddr[g]  = (long)(base0 + prow + lr16) * ld + colo;
    ldsoff[g] = R0 * SLDA;
  }
  const int fr = lane & 15, gi = lane >> 4;
  const int pcol = ((gi ^ ((lane >> 1) & 3)) << 3);
  const int nt = K >> 5;

  auto stage = [&](int t, int buf) {
    const long k0 = (long)t << 5;
    h16* lbase = lds + buf*BUF;
    #pragma unroll
    for (int g = 0; g < 6; ++g)
      gload16(gptr[g] + gaddr[g] + k0, lbase + ldsoff[g]);
  };

  stage(0, 0);
  __syncthreads();
  int cur = 0;
  for (int t = 0; t < nt; ++t) {
    if (t + 1 < nt) stage(t + 1, cur ^ 1);
    h16* base = lds + cur*BUF;
    h16* sAh_ = base;
    h16* sAl_ = base + 128*SLDA;
    h16* sBh_ = base + 256*SLDA;
    h16* sBl_ = base + 512*SLDA;
    h16x8 bh[4], bl[4];
    #pragma unroll
    for (int j = 0; j < 4; ++j) {
      bh[j] = *(const h16x8*)(sBh_ + (wc + j*16 + fr)*SLDA + pcol);
      bl[j] = *(const h16x8*)(sBl_ + (wc + j*16 + fr)*SLDA + pcol);
    }
    __builtin_amdgcn_s_setprio(1);
    #pragma unroll
    for (int i = 0; i < 4; ++i) {
      h16x8 ah = *(const h16x8*)(sAh_ + (wr + i*16 + fr)*SLDA + pcol);
      h16x8 al = *(const h16x8*)(sAl_ + (wr + i*16 + fr)*SLDA + pcol);
      #pragma unroll
      for (int j = 0; j < 4; ++j) {
        acc[i][j] = MFMA16(ah, bh[j], acc[i][j]);
        acc[i][j] = MFMA16(ah, bl[j], acc[i][j]);
        acc[i][j] = MFMA16(al, bh[j], acc[i][j]);
      }
    }
    __builtin_amdgcn_s_setprio(0);
    __syncthreads();
    cur ^= 1;
  }
}

#define EPI_128x256 \
  const int lane = threadIdx.x & 63, wid = threadIdx.x >> 6; \
  const int wr = (wid>>2)*64, wc = (wid&3)*64; \
  const int fr = lane & 15, rb = (lane>>4)*4;

#define EPI_256 \
  const int lane = threadIdx.x & 63, wid = threadIdx.x >> 6; \
  const int wr = (wid>>2)*128, wc = (wid&3)*64; \
  const int fr = lane & 15, rb = (lane>>4)*4;

// ---------------------------------------------------------------------------
// 256x256 f16 SINGLE-PLANE core for MoE, DOUBLE-BUFFERED (verified round 18).
// ---------------------------------------------------------------------------
template<bool GATHER>
__device__ __forceinline__ void hgemm256_core(
    const h16* __restrict__ A, const h16* __restrict__ B,
    int K, int lda, int ldb, int m0, int n0, const int* __restrict__ rowmap,
    f32x4 (&acc)[8][4], h16* lds)
{
  constexpr int BUF = 2*256*SLDA;
  const int tid = threadIdx.x, lane = tid & 63, wid = tid >> 6;
  const int wr = (wid >> 2) * 128, wc = (wid & 3) * 64;
  const int lr16 = lane >> 2, lgrp = lane & 3;
  const int plane = wid >> 2;
  const int qrow  = (wid & 3) * 64;
  const int sw = (lr16 >> 1) & 3;
  const int colo = (lgrp ^ sw) << 3;
  const h16* gp = plane ? B : A;
  const int ld  = plane ? ldb : lda;
  long g0[4];
  #pragma unroll
  for (int g = 0; g < 4; ++g) {
    int lrow = qrow + g*16 + lr16;
    long grow;
    if (GATHER && plane == 0) {
      int t = rowmap[m0 + lrow]; if (t < 0) t = 0;
      grow = t;
    } else {
      grow = (plane ? n0 : m0) + lrow;
    }
    g0[g] = grow * (long)ld + colo;
  }
  const int lo = plane*(256*SLDA) + qrow*SLDA;
  const int fr = lane & 15, gi = lane >> 4;
  const int pcol = ((gi ^ ((lane >> 1) & 3)) << 3);
  const int nt = K >> 5;

  auto stage = [&](int t, int buf) {
    h16* lbase = lds + buf*BUF + lo;
    const long k0 = (long)t << 5;
    #pragma unroll
    for (int g = 0; g < 4; ++g)
      gload16(gp + g0[g] + k0, lbase + (g*16)*SLDA);
  };

  stage(0, 0);
  __syncthreads();
  int cur = 0;
  for (int t = 0; t < nt; ++t) {
    if (t + 1 < nt) stage(t + 1, cur ^ 1);
    h16* base = lds + cur*BUF;
    h16* sA_ = base;
    h16* sB_ = base + 256*SLDA;
    h16x8 b_[4];
    #pragma unroll
    for (int j = 0; j < 4; ++j)
      b_[j] = *(const h16x8*)(sB_ + (wc + j*16 + fr)*SLDA + pcol);
    __builtin_amdgcn_s_setprio(1);
    #pragma unroll
    for (int i = 0; i < 8; ++i) {
      h16x8 a_ = *(const h16x8*)(sA_ + (wr + i*16 + fr)*SLDA + pcol);
      #pragma unroll
      for (int j = 0; j < 4; ++j)
        acc[i][j] = MFMA16(a_, b_[j], acc[i][j]);
    }
    __builtin_amdgcn_s_setprio(0);
    __syncthreads();
    cur ^= 1;
  }
}

// ---------------------------------------------------------------------------
// FUSED prep kernel #1 (BEFORE qkv): counts/cursor zero + input split +
// w3/wo split. Block-range branching; all ranges exact multiples of 256.
// ---------------------------------------------------------------------------
__device__ __forceinline__ void d_split2(const float* __restrict__ a,
                                         h16* __restrict__ H, h16* __restrict__ L,
                                         int i) {
  float4 v = ((const float4*)a)[i];
  float vv[4] = {v.x, v.y, v.z, v.w};
  h16x4 hv, lv;
  #pragma unroll
  for (int q = 0; q < 4; ++q) {
    float x = vv[q] * 64.0f;
    h16 h = (h16)x;
    hv[q] = h;
    lv[q] = (h16)(x - (float)h);
  }
  ((h16x4*)H)[i] = hv;
  ((h16x4*)L)[i] = lv;
}

__global__ __launch_bounds__(256) void k_prep(
    const float* __restrict__ src, const float* __restrict__ pos,
    const float* __restrict__ w3,  const float* __restrict__ wo,
    h16* __restrict__ qkH, h16* __restrict__ qkL,
    h16* __restrict__ sH,  h16* __restrict__ sL,
    h16* __restrict__ W3H, h16* __restrict__ W3L,
    h16* __restrict__ WOH, h16* __restrict__ WOL,
    int* __restrict__ cnt)
{
  const int b = blockIdx.x, tid = threadIdx.x;
  if (b == 0 && tid < 8) cnt[tid] = 0;      // counts[4] + cursor[4]
  if (b < NB_IN) {
    int i = b*256 + tid;
    float4 s = ((const float4*)src)[i];
    float4 p = ((const float4*)pos)[i];
    float sv[4] = {s.x, s.y, s.z, s.w};
    float qv[4] = {s.x+p.x, s.y+p.y, s.z+p.z, s.w+p.w};
    h16x4 sh, sl, qh, ql;
    #pragma unroll
    for (int q = 0; q < 4; ++q) {
      float xs = sv[q] * 16.0f; h16 hs = (h16)xs;
      sh[q] = hs; sl[q] = (h16)(xs - (float)hs);
      float xq = qv[q] * 16.0f; h16 hq = (h16)xq;
      qh[q] = hq; ql[q] = (h16)(xq - (float)hq);
    }
    ((h16x4*)sH)[i] = sh; ((h16x4*)sL)[i] = sl;
    ((h16x4*)qkH)[i] = qh; ((h16x4*)qkL)[i] = ql;
  } else if (b < NB_IN + NB_W3) {
    d_split2(w3, W3H, W3L, (b - NB_IN)*256 + tid);
  } else {
    d_split2(wo, WOH, WOL, (b - NB_IN - NB_W3)*256 + tid);
  }
}

// ---------------------------------------------------------------------------
// FUSED prep kernel #2 (AFTER attn — W1H/W2H alias the dead KL plane!):
// w1 + w2 -> f16.
// ---------------------------------------------------------------------------
__global__ __launch_bounds__(256) void k_prepw(
    const float* __restrict__ w1, const float* __restrict__ w2,
    h16* __restrict__ W1H, h16* __restrict__ W2H)
{
  const int b = blockIdx.x, tid = threadIdx.x;
  const float* a; h16* H; int i;
  if (b < NB_W1) { a = w1; H = W1H; i = b*256 + tid; }
  else           { a = w2; H = W2H; i = (b - NB_W1)*256 + tid; }
  float4 v = ((const float4*)a)[i];
  h16x4 hv;
  hv[0] = (h16)(v.x*64.0f); hv[1] = (h16)(v.y*64.0f);
  hv[2] = (h16)(v.z*64.0f); hv[3] = (h16)(v.w*64.0f);
  ((h16x4*)H)[i] = hv;
}

// ---------------------------------------------------------------------------
// QKV projection (128x256 split dbuf, m-fast XCD mapping; grid 768)
// V-lo not stored (attn is hi-only on V).
// ---------------------------------------------------------------------------
__global__ __launch_bounds__(512) void k_qkv(
    const h16* __restrict__ qkh, const h16* __restrict__ qkl,
    const h16* __restrict__ sh,  const h16* __restrict__ sl,
    const h16* __restrict__ Wh,  const h16* __restrict__ Wl, const float* __restrict__ bias,
    h16* __restrict__ Qh, h16* __restrict__ Ql, h16* __restrict__ Kh, h16* __restrict__ Kl,
    h16* __restrict__ Vh)
{
  __shared__ h16 lds[2*768*SLDA];
  const int bid = blockIdx.x;
  const int xcd = bid & 7, loc = bid >> 3;
  const int m0 = (xcd*8 + (loc & 7)) * 128;
  const int n0 = (loc >> 3) * 256;
  const bool isV = (n0 >= 2048);
  f32x4 acc[4][4] = {};
  gemm128x256_core(isV ? sh : qkh, isV ? sl : qkl, Wh, Wl,
                   1024, 1024, 1024, m0, n0, acc, lds);
  EPI_128x256;
  if (!isV) {
    const bool isK = (n0 >= 1024);
    h16* Hd = isK ? Kh : Qh;
    h16* Ld = isK ? Kl : Ql;
    #pragma unroll
    for (int i = 0; i < 4; ++i)
      #pragma unroll
      for (int j = 0; j < 4; ++j)
        #pragma unroll
        for (int r = 0; r < 4; ++r) {
          int row = m0 + wr + i*16 + rb + r;
          int col = n0 + wc + j*16 + fr;
          float c = acc[i][j][r] * (1.0f/1024.0f) + bias[col];
          int b = row >> 10, s = row & 1023;
          int cc = col & 1023, h = cc >> 6, d = cc & 63;
          long bh = (long)b*NH + h;
          store_split(Hd, Ld, (bh*SEQ + s)*HD + d, c * 16.0f);
        }
  } else {
    #pragma unroll
    for (int i = 0; i < 4; ++i)
      #pragma unroll
      for (int j = 0; j < 4; ++j) {
        int row0 = m0 + wr + i*16 + rb;
        int col  = n0 + wc + j*16 + fr;
        int cc = col & 1023, h = cc >> 6, d = cc & 63;
        float bcol = bias[col];
        h16x4 hv;
        #pragma unroll
        for (int r = 0; r < 4; ++r) {
          float cs = (acc[i][j][r] * (1.0f/1024.0f) + bcol) * 16.0f;
          hv[r] = (h16)cs;
        }
        int b = row0 >> 10, s0 = row0 & 1023;
        long base = ((long)(b*NH + h)*HD + d)*SEQ + s0;
        *(h16x4*)(Vh + base) = hv;
      }
  }
}

// ---------------------------------------------------------------------------
// Fused flash attention, QB=128, dbuf K/V (ONE barrier per tile) + T14 + T13.
// 3 LDS planes (Kh,Kl,Vh; FLD=72 -> 55.3KB dbuf, 16B-aligned rows);
// P hi-only, V hi-only -> single o1 accumulator; PV 8 MFMA/iter.
// ---------------------------------------------------------------------------
__global__ __launch_bounds__(512) void k_attn(
    const h16* __restrict__ Qh, const h16* __restrict__ Ql,
    const h16* __restrict__ Kh, const h16* __restrict__ Kl,
    const h16* __restrict__ Vh,
    h16* __restrict__ Oh, h16* __restrict__ Ol)
{
  constexpr int BUFA = 3*64*FLD;        // 13,824 h16 per buffer
  __shared__ h16 lds[2*BUFA];           // 55,296 B
  const int bid = blockIdx.x;                  // 0..1023
  const int swz = (bid & 7) * 128 + (bid >> 3);
  const int bh = swz >> 3;
  const int q0 = (swz & 7) * QB;
  const int tid = threadIdx.x, lane = tid & 63, w = tid >> 6;
  const int fr = lane & 15, hg = lane >> 4;
  const int kg = hg << 3;
  const long qbase = ((long)bh*SEQ + q0 + w*16 + fr) * HD;
  h16x8 qh[2], ql[2];
  qh[0] = *(const h16x8*)(Qh + qbase + kg);
  qh[1] = *(const h16x8*)(Qh + qbase + 32 + kg);
  ql[0] = *(const h16x8*)(Ql + qbase + kg);
  ql[1] = *(const h16x8*)(Ql + qbase + 32 + kg);
  f32x4 o1[4] = {};
  float mrow = -3.0e38f, lrow = 0.f;
  const int srow = tid >> 3, skc = (tid & 7) << 3;
  const long kbase = ((long)bh*SEQ + srow) * HD + skc;
  const long vbase = ((long)bh*HD + srow) * SEQ + skc;
  const int srcA = fr + ((hg & 1) << 5);
  const int srcB = srcA + 16;
  uint4 rKh, rKl, rVh;
  auto loadt = [&](int kt) {
    const long ka = kbase + (long)(kt*64)*HD;
    rKh = *(const uint4*)(Kh + ka);
    rKl = *(const uint4*)(Kl + ka);
    rVh = *(const uint4*)(Vh + vbase + kt*64);
  };
  auto wbuf = [&](int buf) {
    h16* nb = lds + buf*BUFA;
    *(uint4*)(nb + srow*FLD + skc)            = rKh;
    *(uint4*)(nb + 64*FLD + srow*FLD + skc)   = rKl;
    *(uint4*)(nb + 2*64*FLD + srow*FLD + skc) = rVh;
  };
  loadt(0);
  wbuf(0);
  int cur = 0;
  for (int kt = 0; kt < NCHUNK; ++kt) {
    __syncthreads();                     // publishes buf[cur]; retires prev reads
    if (kt + 1 < NCHUNK) loadt(kt + 1);  // global->reg, hides under compute
    h16* base = lds + cur*BUFA;
    h16* sKh = base;
    h16* sKl = base + 64*FLD;
    h16* sVh = base + 2*64*FLD;
    f32x4 s1[4] = {}, s2[4] = {};
    __builtin_amdgcn_s_setprio(1);
    #pragma unroll
    for (int ks = 0; ks < 2; ++ks)
      #pragma unroll
      for (int j = 0; j < 4; ++j) {
        h16x8 kh = *(const h16x8*)(sKh + (j*16 + fr)*FLD + ks*32 + kg);
        h16x8 kl = *(const h16x8*)(sKl + (j*16 + fr)*FLD + ks*32 + kg);
        s1[j] = MFMA16(kh, qh[ks], s1[j]);
        s2[j] = MFMA16(kh, ql[ks], s2[j]);
        s2[j] = MFMA16(kl, qh[ks], s2[j]);
      }
    __builtin_amdgcn_s_setprio(0);
    float p[4][4];
    float tmax = -3.0e38f;
    #pragma unroll
    for (int j = 0; j < 4; ++j)
      #pragma unroll
      for (int r = 0; r < 4; ++r) {
        float sc = (s1[j][r] + s2[j][r]) * (0.125f/256.0f);
        p[j][r] = sc;
        tmax = fmaxf(tmax, sc);
      }
    tmax = fmaxf(tmax, __shfl_xor(tmax, 16));
    tmax = fmaxf(tmax, __shfl_xor(tmax, 32));
    float mn;
    const bool defer = (__all(tmax - mrow <= 4.0f) != 0);
    float sclf;
    if (defer) {
      mn = mrow;
      sclf = 1.0f;
    } else {
      mn = fmaxf(mrow, tmax);
      sclf = __expf(mrow - mn);
      mrow = mn;
    }
    float psum = 0.f;
    #pragma unroll
    for (int j = 0; j < 4; ++j)
      #pragma unroll
      for (int r = 0; r < 4; ++r) { float e = __expf(p[j][r] - mn); p[j][r] = e; psum += e; }
    psum += __shfl_xor(psum, 16);
    psum += __shfl_xor(psum, 32);
    lrow = lrow*sclf + psum;
    if (!defer) {
      #pragma unroll
      for (int r = 0; r < 4; ++r) {
        float sq = __shfl(sclf, hg*4 + r);
        #pragma unroll
        for (int jd = 0; jd < 4; ++jd) o1[jd][r] *= sq;
      }
    }
    u32 hp[4][2];
    #pragma unroll
    for (int j = 0; j < 4; ++j)
      #pragma unroll
      for (int rp = 0; rp < 2; ++rp)
        hp[j][rp] = pk2w(p[j][2*rp] * 512.0f, p[j][2*rp+1] * 512.0f);
    #pragma unroll
    for (int ks = 0; ks < 2; ++ks) {
      const int j0 = 2*ks, j1 = 2*ks + 1;
      u32 hA0 = (u32)__shfl((int)hp[j0][0], srcA), hA1 = (u32)__shfl((int)hp[j0][1], srcA);
      u32 hB0 = (u32)__shfl((int)hp[j0][0], srcB), hB1 = (u32)__shfl((int)hp[j0][1], srcB);
      u32 hC0 = (u32)__shfl((int)hp[j1][0], srcA), hC1 = (u32)__shfl((int)hp[j1][1], srcA);
      u32 hD0 = (u32)__shfl((int)hp[j1][0], srcB), hD1 = (u32)__shfl((int)hp[j1][1], srcB);
      const bool hij = (hg & 2) != 0;
      union { u32 w[4]; h16x8 v; } pa;
      pa.w[0] = hij ? hC0 : hA0;  pa.w[1] = hij ? hC1 : hA1;
      pa.w[2] = hij ? hD0 : hB0;  pa.w[3] = hij ? hD1 : hB1;
      __builtin_amdgcn_s_setprio(1);
      #pragma unroll
      for (int jd = 0; jd < 4; ++jd) {
        h16x8 vh = *(const h16x8*)(sVh + (jd*16 + fr)*FLD + ks*32 + kg);
        o1[jd] = MFMA16(pa.v, vh, o1[jd]);
      }
      __builtin_amdgcn_s_setprio(0);
    }
    if (kt + 1 < NCHUNK) wbuf(cur ^ 1);  // write next tile; published by next barrier
    cur ^= 1;
  }
  float lq[4];
  #pragma unroll
  for (int r = 0; r < 4; ++r) lq[r] = __shfl(lrow, hg*4 + r);
  const int b = bh >> 4, h = bh & 15;
  #pragma unroll
  for (int jd = 0; jd < 4; ++jd)
    #pragma unroll
    for (int r = 0; r < 4; ++r) {
      int qrow = q0 + w*16 + hg*4 + r;
      int d = jd*16 + fr;
      float ov = o1[jd][r] / (512.0f*16.0f*lq[r]);
      store_split(Oh, Ol, ((long)b*SEQ + qrow)*DM + h*HD + d, ov*16.0f);
    }
}

// out_proj (128x256 split dbuf, m-fast XCD mapping; grid 256)
__global__ __launch_bounds__(512) void k_out(
    const h16* __restrict__ Oh, const h16* __restrict__ Ol,
    const h16* __restrict__ Wh, const h16* __restrict__ Wl,
    const float* __restrict__ bias, float* __restrict__ attn)
{
  __shared__ h16 lds[2*768*SLDA];
  const int bid = blockIdx.x;
  const int xcd = bid & 7, loc = bid >> 3;
  const int m0 = (xcd*8 + (loc & 7)) * 128;
  const int n0 = (loc >> 3) * 256;
  f32x4 acc[4][4] = {};
  gemm128x256_core(Oh, Ol, Wh, Wl, 1024, 1024, 1024, m0, n0, acc, lds);
  EPI_128x256;
  #pragma unroll
  for (int i = 0; i < 4; ++i)
    #pragma unroll
    for (int j = 0; j < 4; ++j)
      #pragma unroll
      for (int r = 0; r < 4; ++r) {
        int row = m0 + wr + i*16 + rb + r;
        int col = n0 + wc + j*16 + fr;
        attn[(long)row*DM + col] = acc[i][j][r] * (1.0f/1024.0f) + bias[col];
      }
}

// ---------------------------------------------------------------------------
// threefry2x32 (key=[0,42]) -> gumbel -> argmax. VERIFIED round 5 — DO NOT TOUCH.
// ---------------------------------------------------------------------------
__device__ __forceinline__ void threefry(u32 x0, u32 x1, u32& y0, u32& y1) {
  const u32 ks0 = 0u, ks1 = 42u, ks2 = 0x1BD11BDAu ^ 42u;
  x0 += ks0; x1 += ks1;
  #define TF_R(r) { x0 += x1; x1 = (x1 << r) | (x1 >> (32 - r)); x1 ^= x0; }
  TF_R(13) TF_R(15) TF_R(26) TF_R(6)  x0 += ks1; x1 += ks2 + 1u;
  TF_R(17) TF_R(29) TF_R(16) TF_R(24) x0 += ks2; x1 += ks0 + 2u;
  TF_R(13) TF_R(15) TF_R(26) TF_R(6)  x0 += ks0; x1 += ks1 + 3u;
  TF_R(17) TF_R(29) TF_R(16) TF_R(24) x0 += ks1; x1 += ks2 + 4u;
  TF_R(13) TF_R(15) TF_R(26) TF_R(6)  x0 += ks2; x1 += ks0 + 5u;
  #undef TF_R
  y0 = x0; y1 = x1;
}

__device__ __forceinline__ float gumbel_from(u32 bits) {
  float f = __uint_as_float((bits >> 9) | 0x3F800000u) - 1.0f;
  float u = (f > 0.0f) ? f : 1.17549435e-38f;
  float nl = (float)(-log((double)u));
  return -(float)log((double)nl);
}

// LN1 + GATE fused
__global__ __launch_bounds__(256) void k_ln1g(
    const float* __restrict__ A, const float* __restrict__ Badd,
    const float* __restrict__ g, const float* __restrict__ be,
    const float* __restrict__ gw, const float* __restrict__ gb,
    float* __restrict__ xout, h16* __restrict__ xh,
    int* __restrict__ chosen, int* __restrict__ counts)
{
  int wave = threadIdx.x >> 6, lane = threadIdx.x & 63;
  long row = (long)blockIdx.x*4 + wave;
  const float* ar = A + row*DM; const float* br = Badd + row*DM;
  float v[16]; float s = 0.0f;
  #pragma unroll
  for (int p = 0; p < 4; ++p) {
    int d = p*256 + lane*4;
    float4 a = *(const float4*)(ar + d);
    float4 b = *(const float4*)(br + d);
    float t0=a.x+b.x, t1=a.y+b.y, t2=a.z+b.z, t3=a.w+b.w;
    v[4*p+0]=t0; v[4*p+1]=t1; v[4*p+2]=t2; v[4*p+3]=t3;
    s += t0+t1+t2+t3;
  }
  s = wave_sum(s);
  float m = s * (1.0f/1024.0f);
  float q = 0.0f;
  #pragma unroll
  for (int i = 0; i < 16; ++i) { float dd = v[i]-m; q += dd*dd; }
  q = wave_sum(q);
  float rs = (float)(1.0 / sqrt((double)(q * (1.0f/1024.0f) + 1e-5f)));
  float pe[4] = {0.f, 0.f, 0.f, 0.f};
  #pragma unroll
  for (int p = 0; p < 4; ++p) {
    int d = p*256 + lane*4;
    float4 gv = *(const float4*)(g + d);
    float4 bv = *(const float4*)(be + d);
    float y0 = (v[4*p+0]-m)*rs*gv.x + bv.x;
    float y1 = (v[4*p+1]-m)*rs*gv.y + bv.y;
    float y2 = (v[4*p+2]-m)*rs*gv.z + bv.z;
    float y3 = (v[4*p+3]-m)*rs*gv.w + bv.w;
    float4 o = {y0,y1,y2,y3};
    *(float4*)(xout + row*DM + d) = o;
    h16x4 hv; hv[0]=(h16)(y0*16.f); hv[1]=(h16)(y1*16.f);
    hv[2]=(h16)(y2*16.f); hv[3]=(h16)(y3*16.f);
    *(h16x4*)(xh + row*DM + d) = hv;
    #pragma unroll
    for (int e = 0; e < 4; ++e) {
      float4 w4 = *(const float4*)(gw + e*DM + d);
      pe[e] += y0*w4.x + y1*w4.y + y2*w4.z + y3*w4.w;
    }
  }
  #pragma unroll
  for (int e = 0; e < 4; ++e) pe[e] = wave_sum(pe[e]);
  if (lane == 0) {
    float best = -3.0e38f; int arg = 0;
    #pragma unroll
    for (int e = 0; e < 4; ++e) {
      float logit = pe[e] + gb[e];
      u32 j = (u32)(4*row + e);
      u32 y0, y1;
      threefry(0u, j, y0, y1);
      float vv = gumbel_from(y0 ^ y1) + logit;
      if (vv > best) { best = vv; arg = e; }
    }
    chosen[(int)row] = arg;
    atomicAdd(&counts[arg], 1);
  }
}

// LayerNorm of (A + Badd) — LN2
__global__ __launch_bounds__(256) void k_ln(
    const float* __restrict__ A, const float* __restrict__ Badd,
    const float* __restrict__ g, const float* __restrict__ be,
    float* __restrict__ dout)
{
  int wave = threadIdx.x >> 6, lane = threadIdx.x & 63;
  long row = (long)blockIdx.x*4 + wave;
  const float* ar = A + row*DM; const float* br = Badd + row*DM;
  float v[16]; float s = 0.0f;
  #pragma unroll
  for (int p = 0; p < 4; ++p) {
    int d = p*256 + lane*4;
    float4 a = *(const float4*)(ar + d);
    float4 b = *(const float4*)(br + d);
    float t0=a.x+b.x, t1=a.y+b.y, t2=a.z+b.z, t3=a.w+b.w;
    v[4*p+0]=t0; v[4*p+1]=t1; v[4*p+2]=t2; v[4*p+3]=t3;
    s += t0+t1+t2+t3;
  }
  s = wave_sum(s);
  float m = s * (1.0f/1024.0f);
  float q = 0.0f;
  #pragma unroll
  for (int i = 0; i < 16; ++i) { float dd = v[i]-m; q += dd*dd; }
  q = wave_sum(q);
  float rs = (float)(1.0 / sqrt((double)(q * (1.0f/1024.0f) + 1e-5f)));
  #pragma unroll
  for (int p = 0; p < 4; ++p) {
    int d = p*256 + lane*4;
    float4 gv = *(const float4*)(g + d);
    float4 bv = *(const float4*)(be + d);
    float y0 = (v[4*p+0]-m)*rs*gv.x + bv.x;
    float y1 = (v[4*p+1]-m)*rs*gv.y + bv.y;
    float y2 = (v[4*p+2]-m)*rs*gv.z + bv.z;
    float y3 = (v[4*p+3]-m)*rs*gv.w + bv.w;
    float4 o = {y0,y1,y2,y3};
    *(float4*)(dout + row*DM + d) = o;
  }
}

// ---------------------------------------------------------------------------
// FUSED bucketing: per-thread local prefix over 4 experts. Grid 40 x 256.
// ---------------------------------------------------------------------------
__global__ __launch_bounds__(256) void k_bucket(
    const int* __restrict__ chosen, const int* __restrict__ counts,
    int* __restrict__ cursor, int* __restrict__ eoff, int* __restrict__ plist)
{
  const int tid = threadIdx.x, b = blockIdx.x;
  const int c0 = counts[0], c1 = counts[1], c2 = counts[2], c3 = counts[3];
  const int p0 = (c0+255)&~255, p1 = (c1+255)&~255, p2 = (c2+255)&~255, p3 = (c3+255)&~255;
  const int o1 = p0, o2 = p0+p1, o3 = p0+p1+p2, end = o3+p3;
  if (b == 0 && tid < 4)
    eoff[tid] = (tid==0) ? 0 : (tid==1) ? o1 : (tid==2) ? o2 : o3;
  if (b < 32) {
    int t = b*256 + tid;
    int e = chosen[t];
    int slot = atomicAdd(&cursor[e], 1);
    int base = (e==0) ? 0 : (e==1) ? o1 : (e==2) ? o2 : o3;
    plist[base + slot] = t;
  } else if (b < 36) {
    int e = b - 32;
    int ce = (e==0) ? c0 : (e==1) ? c1 : (e==2) ? c2 : c3;
    int base = ((e==0) ? 0 : (e==1) ? o1 : (e==2) ? o2 : o3) + ce;
    int pad = (((ce+255)&~255) - ce);
    if (tid < pad) plist[base + tid] = -1;
  } else {
    int idx = end + (b-36)*256 + tid;
    if (idx < NPOS) plist[idx] = -1;
  }
}

// MoE layer 1 (gathered rows, 256^2 f16 dbuf core)
__global__ __launch_bounds__(512, 2) void k_e1(
    const h16* __restrict__ Xh, const h16* __restrict__ W1, const float* __restrict__ b1,
    const int* __restrict__ plist, const int* __restrict__ eoff, h16* __restrict__ Hh)
{
  __shared__ h16 lds[2*2*256*SLDA];
  const int n0 = blockIdx.x*256, m0 = blockIdx.y*256;
  const int e = (m0 >= eoff[1]) + (m0 >= eoff[2]) + (m0 >= eoff[3]);
  f32x4 acc[8][4] = {};
  hgemm256_core<true>(Xh, W1 + (long)e*DFE*DM, 1024, 1024, 1024, m0, n0, plist, acc, lds);
  EPI_256;
  #pragma unroll
  for (int i = 0; i < 8; ++i)
    #pragma unroll
    for (int j = 0; j < 4; ++j)
      #pragma unroll
      for (int r = 0; r < 4; ++r) {
        int row = m0 + wr + i*16 + rb + r;
        int col = n0 + wc + j*16 + fr;
        float c = acc[i][j][r] * (1.0f/1024.0f) + b1[e*DFE + col];
        c = fmaxf(c, 0.0f);
        Hh[(long)row*DFE + col] = (h16)(c * 16.0f);
      }
}

// MoE layer 2 (bucket rows, 256^2 f16 dbuf core, scatter out)
__global__ __launch_bounds__(512, 2) void k_e2(
    const h16* __restrict__ Hh, const h16* __restrict__ W2, const float* __restrict__ b2,
    const int* __restrict__ plist, const int* __restrict__ eoff, float* __restrict__ y)
{
  __shared__ h16 lds[2*2*256*SLDA];
  const int n0 = blockIdx.x*256, m0 = blockIdx.y*256;
  const int e = (m0 >= eoff[1]) + (m0 >= eoff[2]) + (m0 >= eoff[3]);
  f32x4 acc[8][4] = {};
  hgemm256_core<false>(Hh, W2 + (long)e*DM*DFE, 1024, DFE, DFE, m0, n0, nullptr, acc, lds);
  EPI_256;
  #pragma unroll
  for (int i = 0; i < 8; ++i)
    #pragma unroll
    for (int j = 0; j < 4; ++j)
      #pragma unroll
      for (int r = 0; r < 4; ++r) {
        int row = m0 + wr + i*16 + rb + r;
        int col = n0 + wc + j*16 + fr;
        int t = plist[row];
        if (t >= 0)
          y[(long)t*DM + col] = acc[i][j][r] * (1.0f/1024.0f) + b2[e*DM + col];
      }
}

// ---------------------------------------------------------------------------
extern "C" void kernel_launch(void* const* d_in, const int* in_sizes, int n_in,
                              void* d_out, int out_size, void* d_ws, size_t ws_size,
                              hipStream_t stream) {
  const float* src = (const float*)d_in[0];
  const float* pos = (const float*)d_in[1];
  const float* w3  = (const float*)d_in[2];
  const float* b3  = (const float*)d_in[3];
  const float* wo  = (const float*)d_in[4];
  const float* bo  = (const float*)d_in[5];
  const float* gw  = (const float*)d_in[6];
  const float* gb  = (const float*)d_in[7];
  const float* w1  = (const float*)d_in[8];
  const float* b1  = (const float*)d_in[9];
  const float* w2  = (const float*)d_in[10];
  const float* b2  = (const float*)d_in[11];
  const float* g1  = (const float*)d_in[12];
  const float* be1 = (const float*)d_in[13];
  const float* g2  = (const float*)d_in[14];
  const float* be2 = (const float*)d_in[15];
  float* out = (float*)d_out;
  char* ws = (char*)d_ws;
  if (ws_size < WS_NEEDED) return;

  auto H = [&](size_t off) { return (h16*)(ws + off); };
  auto F = [&](size_t off) { return (float*)(ws + off); };
  auto I = [&](size_t off) { return (int*)(ws + off); };

  // 1) zero + input/w3/wo conversion (W1/W2 must wait: they alias KL)
  k_prep<<<dim3(NB_PREP), 256, 0, stream>>>(
      src, pos, w3, wo,
      H(OFF_QKH), H(OFF_QKL), H(OFF_SRCH), H(OFF_SRCL),
      H(OFF_W3H), H(OFF_W3L), H(OFF_WOH), H(OFF_WOL), I(OFF_COUNTS));

  // 2) QKV projection (128x256 dbuf, grid 768 = 3 full rounds)
  k_qkv<<<dim3(768), 512, 0, stream>>>(
      H(OFF_QKH), H(OFF_QKL), H(OFF_SRCH), H(OFF_SRCL), H(OFF_W3H), H(OFF_W3L), b3,
      H(OFF_QH), H(OFF_QL), H(OFF_KH), H(OFF_KL), H(OFF_VH));

  // 3) fused flash attention (QB=128, dbuf K/V, T14+T13, hi-only P/V)
  k_attn<<<dim3(NBH*(SEQ/QB)), 512, 0, stream>>>(
      H(OFF_QH), H(OFF_QL), H(OFF_KH), H(OFF_KL), H(OFF_VH),
      H(OFF_OH), H(OFF_OL));

  // 4) w1/w2 -> f16 (KL is dead now; W1H/W2H occupy its plane)
  k_prepw<<<dim3(NB_PREPW), 256, 0, stream>>>(w1, w2, H(OFF_W1H), H(OFF_W2H));

  // 5) out projection (grid 256 = 1 full round)
  k_out<<<dim3(256), 512, 0, stream>>>(
      H(OFF_OH), H(OFF_OL), H(OFF_WOH), H(OFF_WOL), bo, F(OFF_ATT));

  // 6) LN1 + gate
  k_ln1g<<<BS/4, 256, 0, stream>>>(src, F(OFF_ATT), g1, be1, gw, gb,
      F(OFF_X), H(OFF_XH), I(OFF_CHOSEN), I(OFF_COUNTS));

  // 7) bucketing in ONE launch (offsets+fill+scatter)
  k_bucket<<<dim3(40), 256, 0, stream>>>(
      I(OFF_CHOSEN), I(OFF_COUNTS), I(OFF_CURSOR), I(OFF_EOFF), I(OFF_PLIST));

  // 8-9) MoE (256^2 f16 dbuf cores)
  k_e1<<<dim3(DFE/256, NPOS/256), 512, 0, stream>>>(
      H(OFF_XH), H(OFF_W1H), b1, I(OFF_PLIST), I(OFF_EOFF), H(OFF_HH));
  k_e2<<<dim3(DM/256, NPOS/256), 512, 0, stream>>>(
      H(OFF_HH), H(OFF_W2H), b2, I(OFF_PLIST), I(OFF_EOFF), F(OFF_Y));

  // 10) final LN2 -> output
  k_ln<<<BS/4, 256, 0, stream>>>(F(OFF_X), F(OFF_Y), g2, be2, out);
}